// Round 1
// baseline (231.967 us; speedup 1.0000x reference)
//
#include <hip/hip_runtime.h>
#include <math.h>

namespace {

constexpr int IMG  = 128;
constexpr int NPIX = IMG * IMG;
constexpr int B    = 4;
constexpr int V    = 600;
constexpr int F    = 1000;
constexpr float FOCALF = 1.5f;
constexpr float EPSF   = 1e-8f;

__device__ inline float seg_dist2(float px, float py, float ax, float ay,
                                  float bx, float by) {
#pragma clang fp contract(off)
    float ex = bx - ax, ey = by - ay;
    float dx = px - ax, dy = py - ay;
    float ee = fmaxf(ex * ex + ey * ey, EPSF);
    float t  = (dx * ex + dy * ey) / ee;
    t = fminf(fmaxf(t, 0.0f), 1.0f);
    float rx = dx - t * ex;
    float ry = dy - t * ey;
    return rx * rx + ry * ry;
}

// grid: B*64 blocks, 256 threads. Each block: one batch image, 256 pixels.
// LDS: projected verts (7.2KB) + per-face SoA (40KB) = 47.2KB.
__global__ __launch_bounds__(256) void rast_kernel(const float* __restrict__ verts,
                                                   const int* __restrict__ faces,
                                                   float* __restrict__ out) {
#pragma clang fp contract(off)
    __shared__ float svx[V], svy[V], svz[V];
    __shared__ float fax[F], fay[F], faz_[F];
    __shared__ float fbx[F], fby[F], fbz[F];
    __shared__ float fcx[F], fcy[F], fcz[F];
    __shared__ float fden[F];

    const int tid  = threadIdx.x;
    const int b    = blockIdx.x >> 6;   // 64 blocks per image
    const int tile = blockIdx.x & 63;

    // 1) project this batch's vertices to NDC (matches: FOCAL*x/z left-to-right)
    for (int i = tid; i < V; i += 256) {
        float x = verts[(b * V + i) * 3 + 0];
        float y = verts[(b * V + i) * 3 + 1];
        float z = verts[(b * V + i) * 3 + 2];
        svx[i] = (FOCALF * x) / z;
        svy[i] = (FOCALF * y) / z;
        svz[i] = z;
    }
    __syncthreads();

    // 2) gather per-face vertex data + signed-area denom (0 marks degenerate)
    for (int f = tid; f < F; f += 256) {
        int i0 = faces[f * 3 + 0], i1 = faces[f * 3 + 1], i2 = faces[f * 3 + 2];
        float ax = svx[i0], ay = svy[i0];
        float bx = svx[i1], by = svy[i1];
        float cx = svx[i2], cy = svy[i2];
        float area = (bx - ax) * (cy - ay) - (by - ay) * (cx - ax);
        fax[f] = ax; fay[f] = ay; faz_[f] = svz[i0];
        fbx[f] = bx; fby[f] = by; fbz[f]  = svz[i1];
        fcx[f] = cx; fcy[f] = cy; fcz[f]  = svz[i2];
        fden[f] = (fabsf(area) > EPSF) ? area : 0.0f;
    }
    __syncthreads();

    // 3) per-pixel brute-force z-argmin over faces (first-min wins, like jnp.argmin)
    const int p  = tile * 256 + tid;
    const int ix = p & (IMG - 1);
    const int iy = p >> 7;
    const float px = 1.0f - (2.0f * (float)ix + 1.0f) / (float)IMG;
    const float py = 1.0f - (2.0f * (float)iy + 1.0f) / (float)IMG;

    float zmin = INFINITY;
    int   best = -1;
    float bb0 = -1.0f, bb1 = -1.0f, bb2 = -1.0f;

    for (int f = 0; f < F; ++f) {
        float den = fden[f];
        float ax = fax[f], ay = fay[f];
        float bx = fbx[f], by = fby[f];
        float cx = fcx[f], cy = fcy[f];
        // edge functions exactly as reference (contract off: no fma reassoc)
        float w0 = (cx - bx) * (py - by) - (cy - by) * (px - bx);
        float w1 = (ax - cx) * (py - cy) - (ay - cy) * (px - cx);
        float w2 = (bx - ax) * (py - ay) - (by - ay) * (px - ax);
        float s0 = w0 / den, s1 = w1 / den, s2 = w2 / den;
        float z  = s0 * faz_[f] + s1 * fbz[f] + s2 * fcz[f];
        bool inside = (s0 >= 0.0f) & (s1 >= 0.0f) & (s2 >= 0.0f) &
                      (den != 0.0f) & (z > 0.0f);
        if (inside && z < zmin) {
            zmin = z; best = f;
            bb0 = s0; bb1 = s1; bb2 = s2;
        }
    }

    // 4) epilogue: winner's edge distances, write 4 outputs (all as float32)
    float o_face = -1.0f, o_z = -1.0f, o_b0 = -1.0f, o_b1 = -1.0f,
          o_b2 = -1.0f, o_d = -1.0f;
    if (best >= 0) {
        float ax = fax[best], ay = fay[best];
        float bx = fbx[best], by = fby[best];
        float cx = fcx[best], cy = fcy[best];
        float d2 = fminf(fminf(seg_dist2(px, py, ax, ay, bx, by),
                               seg_dist2(px, py, bx, by, cx, cy)),
                         seg_dist2(px, py, cx, cy, ax, ay));
        o_face = (float)best;
        o_z    = zmin;
        o_b0 = bb0; o_b1 = bb1; o_b2 = bb2;
        o_d  = -d2;
    }

    const int gp = b * NPIX + p;
    out[gp]               = o_face;                  // pix_to_face (B,H,W)
    out[B * NPIX + gp]    = o_z;                     // zbuf        (B,H,W)
    const int bary_base = 2 * B * NPIX;
    out[bary_base + gp * 3 + 0] = o_b0;              // bary        (B,H,W,3)
    out[bary_base + gp * 3 + 1] = o_b1;
    out[bary_base + gp * 3 + 2] = o_b2;
    out[5 * B * NPIX + gp] = o_d;                    // dists       (B,H,W)
}

} // namespace

extern "C" void kernel_launch(void* const* d_in, const int* in_sizes, int n_in,
                              void* d_out, int out_size, void* d_ws, size_t ws_size,
                              hipStream_t stream) {
    const float* verts = (const float*)d_in[0];  // (B,V,3) f32
    const int*   faces = (const int*)d_in[1];    // (F,3) i32
    float* out = (float*)d_out;                  // concat: p2f|zbuf|bary|dists
    rast_kernel<<<dim3(B * 64), dim3(256), 0, stream>>>(verts, faces, out);
}

// Round 2
// 100.013 us; speedup vs baseline: 2.3194x; 2.3194x over previous
//
#include <hip/hip_runtime.h>
#include <math.h>

namespace {

constexpr int IMG  = 128;
constexpr int NPIX = IMG * IMG;
constexpr int B    = 4;
constexpr int V    = 600;
constexpr int F    = 1000;
constexpr int NCHUNK = 8;
constexpr int CHUNK  = F / NCHUNK;   // 125
constexpr float FOCALF = 1.5f;
constexpr float EPSF   = 1e-8f;

__device__ inline float seg_dist2(float px, float py, float ax, float ay,
                                  float bx, float by) {
#pragma clang fp contract(off)
    float ex = bx - ax, ey = by - ay;
    float dx = px - ax, dy = py - ay;
    float ee = fmaxf(ex * ex + ey * ey, EPSF);
    float t  = (dx * ex + dy * ey) / ee;
    t = fminf(fmaxf(t, 0.0f), 1.0f);
    float rx = dx - t * ex;
    float ry = dy - t * ey;
    return rx * rx + ry * ry;
}

// Pass 1: grid (B*64 tiles, NCHUNK chunks) x 256 threads.
// Each block: one 16x16 pixel tile of one image, 125 faces. Local argmin in
// registers, then one packed-u64 atomicMin per pixel.
__global__ __launch_bounds__(256) void pass1(const float* __restrict__ verts,
                                             const int* __restrict__ faces,
                                             unsigned long long* __restrict__ zbest) {
#pragma clang fp contract(off)
    __shared__ float svx[V], svy[V], svz[V];
    __shared__ float fax[CHUNK], fay[CHUNK], faz_[CHUNK];
    __shared__ float fbx[CHUNK], fby[CHUNK], fbz[CHUNK];
    __shared__ float fcx[CHUNK], fcy[CHUNK], fcz[CHUNK];
    __shared__ float fden[CHUNK];

    const int tid   = threadIdx.x;
    const int b     = blockIdx.x >> 6;
    const int tile  = blockIdx.x & 63;
    const int fbase = blockIdx.y * CHUNK;

    // project this image's vertices to NDC (exact reference formula)
    for (int i = tid; i < V; i += 256) {
        float x = verts[(b * V + i) * 3 + 0];
        float y = verts[(b * V + i) * 3 + 1];
        float z = verts[(b * V + i) * 3 + 2];
        svx[i] = (FOCALF * x) / z;
        svy[i] = (FOCALF * y) / z;
        svz[i] = z;
    }
    __syncthreads();

    if (tid < CHUNK) {
        int f  = fbase + tid;
        int i0 = faces[f * 3 + 0], i1 = faces[f * 3 + 1], i2 = faces[f * 3 + 2];
        float ax = svx[i0], ay = svy[i0];
        float bx = svx[i1], by = svy[i1];
        float cx = svx[i2], cy = svy[i2];
        float area = (bx - ax) * (cy - ay) - (by - ay) * (cx - ax);
        fax[tid] = ax; fay[tid] = ay; faz_[tid] = svz[i0];
        fbx[tid] = bx; fby[tid] = by; fbz[tid]  = svz[i1];
        fcx[tid] = cx; fcy[tid] = cy; fcz[tid]  = svz[i2];
        fden[tid] = (fabsf(area) > EPSF) ? area : 0.0f;   // 0 marks degenerate
    }
    __syncthreads();

    // wave-compact pixel footprint: 16x16 tile, each wave covers 16x4 px
    const int dx = tid & 15, dy = tid >> 4;
    const int ix = (tile & 7) * 16 + dx;
    const int iy = (tile >> 3) * 16 + dy;
    const float px = 1.0f - (2.0f * (float)ix + 1.0f) / (float)IMG;
    const float py = 1.0f - (2.0f * (float)iy + 1.0f) / (float)IMG;

    float zmin = INFINITY;
    int   best = -1;

    for (int f = 0; f < CHUNK; ++f) {
        float den = fden[f];
        float ax = fax[f], ay = fay[f];
        float bx = fbx[f], by = fby[f];
        float cx = fcx[f], cy = fcy[f];
        float w0 = (cx - bx) * (py - by) - (cy - by) * (px - bx);
        float w1 = (ax - cx) * (py - cy) - (ay - cy) * (px - cx);
        float w2 = (bx - ax) * (py - ay) - (by - ay) * (px - ax);
        // sign test: s_i = w_i/den >= 0  <=>  w_i==0 || sign(w_i)==sign(den)
        unsigned ds = __float_as_uint(den) >> 31;
        bool in0 = (w0 == 0.0f) || ((__float_as_uint(w0) >> 31) == ds);
        bool in1 = (w1 == 0.0f) || ((__float_as_uint(w1) >> 31) == ds);
        bool in2 = (w2 == 0.0f) || ((__float_as_uint(w2) >> 31) == ds);
        if ((den != 0.0f) & in0 & in1 & in2) {
            // expensive path only for candidate faces (exact ref rounding)
            float s0 = w0 / den, s1 = w1 / den, s2 = w2 / den;
            float z  = s0 * faz_[f] + s1 * fbz[f] + s2 * fcz[f];
            if (z > 0.0f && z < zmin) { zmin = z; best = fbase + f; }
        }
    }

    if (best >= 0) {
        unsigned long long packed =
            ((unsigned long long)__float_as_uint(zmin) << 32) | (unsigned)best;
        atomicMin(&zbest[b * NPIX + iy * IMG + ix], packed);
    }
}

// Pass 2: unpack winner, recompute bary (identical formulas/rounding) + dists.
__global__ __launch_bounds__(256) void pass2(const float* __restrict__ verts,
                                             const int* __restrict__ faces,
                                             const unsigned long long* __restrict__ zbest,
                                             float* __restrict__ out) {
#pragma clang fp contract(off)
    const int gp = blockIdx.x * 256 + threadIdx.x;  // 0..B*NPIX-1
    const int b  = gp >> 14;                         // NPIX = 2^14
    const int p  = gp & (NPIX - 1);
    const int ix = p & (IMG - 1), iy = p >> 7;

    unsigned long long packed = zbest[gp];
    float o_face = -1.0f, o_z = -1.0f, o_b0 = -1.0f, o_b1 = -1.0f,
          o_b2 = -1.0f, o_d = -1.0f;

    if (packed != ~0ULL) {
        const int   idx = (int)(unsigned)(packed & 0xffffffffu);
        const float z   = __uint_as_float((unsigned)(packed >> 32));
        const float px  = 1.0f - (2.0f * (float)ix + 1.0f) / (float)IMG;
        const float py  = 1.0f - (2.0f * (float)iy + 1.0f) / (float)IMG;

        int i0 = faces[idx * 3 + 0], i1 = faces[idx * 3 + 1], i2 = faces[idx * 3 + 2];
        float v0x = verts[(b * V + i0) * 3 + 0], v0y = verts[(b * V + i0) * 3 + 1],
              v0z = verts[(b * V + i0) * 3 + 2];
        float v1x = verts[(b * V + i1) * 3 + 0], v1y = verts[(b * V + i1) * 3 + 1],
              v1z = verts[(b * V + i1) * 3 + 2];
        float v2x = verts[(b * V + i2) * 3 + 0], v2y = verts[(b * V + i2) * 3 + 1],
              v2z = verts[(b * V + i2) * 3 + 2];
        float ax = (FOCALF * v0x) / v0z, ay = (FOCALF * v0y) / v0z;
        float bx = (FOCALF * v1x) / v1z, by = (FOCALF * v1y) / v1z;
        float cx = (FOCALF * v2x) / v2z, cy = (FOCALF * v2y) / v2z;

        float den = (bx - ax) * (cy - ay) - (by - ay) * (cx - ax); // |den|>EPS for winner
        float w0 = (cx - bx) * (py - by) - (cy - by) * (px - bx);
        float w1 = (ax - cx) * (py - cy) - (ay - cy) * (px - cx);
        float w2 = (bx - ax) * (py - ay) - (by - ay) * (px - ax);
        float s0 = w0 / den, s1 = w1 / den, s2 = w2 / den;

        float d2 = fminf(fminf(seg_dist2(px, py, ax, ay, bx, by),
                               seg_dist2(px, py, bx, by, cx, cy)),
                         seg_dist2(px, py, cx, cy, ax, ay));
        o_face = (float)idx; o_z = z;
        o_b0 = s0; o_b1 = s1; o_b2 = s2;
        o_d = -d2;
    }

    out[gp]            = o_face;
    out[B * NPIX + gp] = o_z;
    const int bary_base = 2 * B * NPIX;
    out[bary_base + gp * 3 + 0] = o_b0;
    out[bary_base + gp * 3 + 1] = o_b1;
    out[bary_base + gp * 3 + 2] = o_b2;
    out[5 * B * NPIX + gp] = o_d;
}

} // namespace

extern "C" void kernel_launch(void* const* d_in, const int* in_sizes, int n_in,
                              void* d_out, int out_size, void* d_ws, size_t ws_size,
                              hipStream_t stream) {
    const float* verts = (const float*)d_in[0];  // (B,V,3) f32
    const int*   faces = (const int*)d_in[1];    // (F,3) i32
    float* out = (float*)d_out;
    unsigned long long* zbest = (unsigned long long*)d_ws;  // B*NPIX u64 = 512KB

    hipMemsetAsync(zbest, 0xFF, (size_t)B * NPIX * sizeof(unsigned long long), stream);
    pass1<<<dim3(B * 64, NCHUNK), dim3(256), 0, stream>>>(verts, faces, zbest);
    pass2<<<dim3(B * NPIX / 256), dim3(256), 0, stream>>>(verts, faces, zbest, out);
}

// Round 3
// 52.237 us; speedup vs baseline: 4.4406x; 1.9146x over previous
//
#include <hip/hip_runtime.h>
#include <math.h>

namespace {

constexpr int IMG  = 128;
constexpr int NPIX = IMG * IMG;
constexpr int B    = 4;
constexpr int V    = 600;
constexpr int F    = 1000;
constexpr int NCHUNK = 16;
constexpr int CHUNK  = 64;          // 16*64 = 1024 >= F (guarded)
constexpr float FOCALF = 1.5f;
constexpr float EPSF   = 1e-8f;
constexpr float SLACK  = 1e-5f;     // >> max rounding error of w (~3e-6)

__device__ inline float seg_dist2(float px, float py, float ax, float ay,
                                  float bx, float by) {
#pragma clang fp contract(off)
    float ex = bx - ax, ey = by - ay;
    float dx = px - ax, dy = py - ay;
    float ee = fmaxf(ex * ex + ey * ey, EPSF);
    float t  = (dx * ex + dy * ey) / ee;
    t = fminf(fmaxf(t, 0.0f), 1.0f);
    float rx = dx - t * ex;
    float ry = dy - t * ey;
    return rx * rx + ry * ry;
}

// facedata layout [b][f][16]:
//  0:e0x 1:e0y 2:bx 3:by | 4:e1x 5:e1y 6:cx 7:cy | 8:e2x 9:e2y 10:ax 11:ay |
// 12:den 13:az 14:bz 15:cz      (den==0 marks degenerate/culled)
__global__ __launch_bounds__(256) void setup(const float* __restrict__ verts,
                                             const int* __restrict__ faces,
                                             float* __restrict__ fdata) {
#pragma clang fp contract(off)
    int t = blockIdx.x * 256 + threadIdx.x;
    if (t >= B * F) return;
    int b = t / F, f = t - b * F;
    int i0 = faces[f * 3 + 0], i1 = faces[f * 3 + 1], i2 = faces[f * 3 + 2];
    const float* vb = verts + (size_t)b * V * 3;
    float x0 = vb[i0 * 3], y0 = vb[i0 * 3 + 1], z0 = vb[i0 * 3 + 2];
    float x1 = vb[i1 * 3], y1 = vb[i1 * 3 + 1], z1 = vb[i1 * 3 + 2];
    float x2 = vb[i2 * 3], y2 = vb[i2 * 3 + 1], z2 = vb[i2 * 3 + 2];
    // exact reference projection
    float ax = (FOCALF * x0) / z0, ay = (FOCALF * y0) / z0;
    float bx = (FOCALF * x1) / z1, by = (FOCALF * y1) / z1;
    float cx = (FOCALF * x2) / z2, cy = (FOCALF * y2) / z2;
    // edge vectors (identical rounding to reference's inline subtractions)
    float e0x = cx - bx, e0y = cy - by;   // edge for w0 (v1->v2), base b
    float e1x = ax - cx, e1y = ay - cy;   // edge for w1 (v2->v0), base c
    float e2x = bx - ax, e2y = by - ay;   // edge for w2 (v0->v1), base a
    float den = e2x * (cy - ay) - e2y * (cx - ax);   // == reference area tree
    if (!(fabsf(den) > EPSF)) den = 0.0f;
    float* o = fdata + ((size_t)t << 4);
    o[0]  = e0x; o[1]  = e0y; o[2]  = bx;  o[3]  = by;
    o[4]  = e1x; o[5]  = e1y; o[6]  = cx;  o[7]  = cy;
    o[8]  = e2x; o[9]  = e2y; o[10] = ax;  o[11] = ay;
    o[12] = den; o[13] = z0;  o[14] = z1;  o[15] = z2;
}

// one block = (image b, 16x16 pixel tile, chunk of 64 faces)
__global__ __launch_bounds__(256) void pass1(const float* __restrict__ fdata,
                                             unsigned long long* __restrict__ zbest) {
#pragma clang fp contract(off)
    __shared__ int sidx[CHUNK];
    __shared__ int scnt;
    const int tid   = threadIdx.x;
    const int b     = blockIdx.x >> 6;
    const int tile  = blockIdx.x & 63;
    const int fbase = blockIdx.y * CHUNK;
    if (tid == 0) scnt = 0;
    __syncthreads();

    const int ix0 = (tile & 7) * 16, iy0 = (tile >> 3) * 16;
    const float pxmax = 1.0f - (2.0f * (float)ix0 + 1.0f) / (float)IMG;
    const float pxmin = 1.0f - (2.0f * (float)(ix0 + 15) + 1.0f) / (float)IMG;
    const float pymax = 1.0f - (2.0f * (float)iy0 + 1.0f) / (float)IMG;
    const float pymin = 1.0f - (2.0f * (float)(iy0 + 15) + 1.0f) / (float)IMG;

    // conservative half-plane binning: survive iff for all 3 edges,
    // max over tile rect of sign(den)*w_exact >= -SLACK
    if (tid < CHUNK && fbase + tid < F) {
        const int f = fbase + tid;
        const float4* fd4 = (const float4*)(fdata + (((size_t)b * F + f) << 4));
        float4 q0 = fd4[0], q1 = fd4[1], q2 = fd4[2], q3 = fd4[3];
        float den = q3.x;
        if (den != 0.0f) {
            float s = den > 0.0f ? 1.0f : -1.0f;
            bool pass = true;
            {
                float gx = s * q0.x, gy = s * q0.y;
                float pyc = gx >= 0.0f ? pymax : pymin;
                float pxc = gy >= 0.0f ? pxmin : pxmax;
                pass &= (gx * (pyc - q0.w) - gy * (pxc - q0.z)) >= -SLACK;
            }
            {
                float gx = s * q1.x, gy = s * q1.y;
                float pyc = gx >= 0.0f ? pymax : pymin;
                float pxc = gy >= 0.0f ? pxmin : pxmax;
                pass &= (gx * (pyc - q1.w) - gy * (pxc - q1.z)) >= -SLACK;
            }
            {
                float gx = s * q2.x, gy = s * q2.y;
                float pyc = gx >= 0.0f ? pymax : pymin;
                float pxc = gy >= 0.0f ? pxmin : pxmax;
                pass &= (gx * (pyc - q2.w) - gy * (pxc - q2.z)) >= -SLACK;
            }
            if (pass) { int slot = atomicAdd(&scnt, 1); sidx[slot] = f; }
        }
    }
    __syncthreads();
    const int cnt = scnt;

    const int dx = tid & 15, dy = tid >> 4;
    const int ix = ix0 + dx, iy = iy0 + dy;
    const float px = 1.0f - (2.0f * (float)ix + 1.0f) / (float)IMG;
    const float py = 1.0f - (2.0f * (float)iy + 1.0f) / (float)IMG;

    unsigned long long pmin = ~0ULL;
    for (int i = 0; i < cnt; ++i) {
        const int fj = __builtin_amdgcn_readfirstlane(sidx[i]);
        const float4* fd4 = (const float4*)(fdata + (((size_t)b * F + fj) << 4));
        float4 q0 = fd4[0], q1 = fd4[1], q2 = fd4[2], q3 = fd4[3];
        const float den = q3.x;
        // exact reference edge functions
        float w0 = q0.x * (py - q0.w) - q0.y * (px - q0.z);
        float w1 = q1.x * (py - q1.w) - q1.y * (px - q1.z);
        float w2 = q2.x * (py - q2.w) - q2.y * (px - q2.z);
        // s_i >= 0  <=>  w_i==0 || sign(w_i)==sign(den)   (den != 0 here)
        unsigned ds = __float_as_uint(den) >> 31;
        bool in0 = (w0 == 0.0f) || ((__float_as_uint(w0) >> 31) == ds);
        bool in1 = (w1 == 0.0f) || ((__float_as_uint(w1) >> 31) == ds);
        bool in2 = (w2 == 0.0f) || ((__float_as_uint(w2) >> 31) == ds);
        if (in0 & in1 & in2) {
            // exact reference rounding for z (3 IEEE divides)
            float s0 = w0 / den, s1 = w1 / den, s2 = w2 / den;
            float z  = s0 * q3.y + s1 * q3.z + s2 * q3.w;
            if (z > 0.0f) {
                unsigned long long pk =
                    ((unsigned long long)__float_as_uint(z) << 32) | (unsigned)fj;
                pmin = pmin < pk ? pmin : pk;
            }
        }
    }
    if (pmin != ~0ULL) atomicMin(&zbest[b * NPIX + iy * IMG + ix], pmin);
}

__global__ __launch_bounds__(256) void pass2(const float* __restrict__ verts,
                                             const int* __restrict__ faces,
                                             const unsigned long long* __restrict__ zbest,
                                             float* __restrict__ out) {
#pragma clang fp contract(off)
    const int gp = blockIdx.x * 256 + threadIdx.x;
    const int b  = gp >> 14;
    const int p  = gp & (NPIX - 1);
    const int ix = p & (IMG - 1), iy = p >> 7;

    unsigned long long packed = zbest[gp];
    float o_face = -1.0f, o_z = -1.0f, o_b0 = -1.0f, o_b1 = -1.0f,
          o_b2 = -1.0f, o_d = -1.0f;

    if (packed != ~0ULL) {
        const int   idx = (int)(unsigned)(packed & 0xffffffffu);
        const float z   = __uint_as_float((unsigned)(packed >> 32));
        const float px  = 1.0f - (2.0f * (float)ix + 1.0f) / (float)IMG;
        const float py  = 1.0f - (2.0f * (float)iy + 1.0f) / (float)IMG;

        int i0 = faces[idx * 3 + 0], i1 = faces[idx * 3 + 1], i2 = faces[idx * 3 + 2];
        const float* vb = verts + (size_t)b * V * 3;
        float v0x = vb[i0 * 3], v0y = vb[i0 * 3 + 1], v0z = vb[i0 * 3 + 2];
        float v1x = vb[i1 * 3], v1y = vb[i1 * 3 + 1], v1z = vb[i1 * 3 + 2];
        float v2x = vb[i2 * 3], v2y = vb[i2 * 3 + 1], v2z = vb[i2 * 3 + 2];
        float ax = (FOCALF * v0x) / v0z, ay = (FOCALF * v0y) / v0z;
        float bx = (FOCALF * v1x) / v1z, by = (FOCALF * v1y) / v1z;
        float cx = (FOCALF * v2x) / v2z, cy = (FOCALF * v2y) / v2z;

        float den = (bx - ax) * (cy - ay) - (by - ay) * (cx - ax);
        float w0 = (cx - bx) * (py - by) - (cy - by) * (px - bx);
        float w1 = (ax - cx) * (py - cy) - (ay - cy) * (px - cx);
        float w2 = (bx - ax) * (py - ay) - (by - ay) * (px - ax);
        float s0 = w0 / den, s1 = w1 / den, s2 = w2 / den;

        float d2 = fminf(fminf(seg_dist2(px, py, ax, ay, bx, by),
                               seg_dist2(px, py, bx, by, cx, cy)),
                         seg_dist2(px, py, cx, cy, ax, ay));
        o_face = (float)idx; o_z = z;
        o_b0 = s0; o_b1 = s1; o_b2 = s2;
        o_d = -d2;
    }

    out[gp]            = o_face;
    out[B * NPIX + gp] = o_z;
    const int bary_base = 2 * B * NPIX;
    out[bary_base + gp * 3 + 0] = o_b0;
    out[bary_base + gp * 3 + 1] = o_b1;
    out[bary_base + gp * 3 + 2] = o_b2;
    out[5 * B * NPIX + gp] = o_d;
}

} // namespace

extern "C" void kernel_launch(void* const* d_in, const int* in_sizes, int n_in,
                              void* d_out, int out_size, void* d_ws, size_t ws_size,
                              hipStream_t stream) {
    const float* verts = (const float*)d_in[0];  // (B,V,3) f32
    const int*   faces = (const int*)d_in[1];    // (F,3) i32
    float* out = (float*)d_out;

    unsigned long long* zbest = (unsigned long long*)d_ws;          // 512 KB
    float* fdata = (float*)((char*)d_ws + (size_t)B * NPIX * 8);    // 256 KB

    hipMemsetAsync(zbest, 0xFF, (size_t)B * NPIX * sizeof(unsigned long long), stream);
    setup<<<(B * F + 255) / 256, 256, 0, stream>>>(verts, faces, fdata);
    pass1<<<dim3(B * 64, NCHUNK), dim3(256), 0, stream>>>(fdata, zbest);
    pass2<<<dim3(B * NPIX / 256), dim3(256), 0, stream>>>(verts, faces, zbest, out);
}

// Round 4
// 50.528 us; speedup vs baseline: 4.5908x; 1.0338x over previous
//
#include <hip/hip_runtime.h>
#include <math.h>

namespace {

constexpr int IMG  = 128;
constexpr int NPIX = IMG * IMG;
constexpr int B    = 4;
constexpr int V    = 600;
constexpr int F    = 1000;
constexpr int NCHUNK = 16;
constexpr int CHUNK  = 64;          // 16*64 = 1024 >= F (guarded)
constexpr float FOCALF = 1.5f;
constexpr float EPSF   = 1e-8f;
constexpr float SLACK  = 1e-5f;     // >> max rounding error of w (~3e-6)

__device__ inline float seg_dist2(float px, float py, float ax, float ay,
                                  float bx, float by) {
#pragma clang fp contract(off)
    float ex = bx - ax, ey = by - ay;
    float dx = px - ax, dy = py - ay;
    float ee = fmaxf(ex * ex + ey * ey, EPSF);
    float t  = (dx * ex + dy * ey) / ee;
    t = fminf(fmaxf(t, 0.0f), 1.0f);
    float rx = dx - t * ex;
    float ry = dy - t * ey;
    return rx * rx + ry * ry;
}

// facedata layout [b][f][16]:
//  0:e0x 1:e0y 2:bx 3:by | 4:e1x 5:e1y 6:cx 7:cy | 8:e2x 9:e2y 10:ax 11:ay |
// 12:den 13:az 14:bz 15:cz      (den==0 marks degenerate/culled)
// Also clears zbest (one u64 per pixel) — fused to save a launch.
__global__ __launch_bounds__(256) void setup_clear(const float* __restrict__ verts,
                                                   const int* __restrict__ faces,
                                                   float* __restrict__ fdata,
                                                   unsigned long long* __restrict__ zbest) {
#pragma clang fp contract(off)
    int t = blockIdx.x * 256 + threadIdx.x;   // grid covers B*NPIX = 65536
    zbest[t] = ~0ULL;
    if (t >= B * F) return;
    int b = t / F, f = t - b * F;
    int i0 = faces[f * 3 + 0], i1 = faces[f * 3 + 1], i2 = faces[f * 3 + 2];
    const float* vb = verts + (size_t)b * V * 3;
    float x0 = vb[i0 * 3], y0 = vb[i0 * 3 + 1], z0 = vb[i0 * 3 + 2];
    float x1 = vb[i1 * 3], y1 = vb[i1 * 3 + 1], z1 = vb[i1 * 3 + 2];
    float x2 = vb[i2 * 3], y2 = vb[i2 * 3 + 1], z2 = vb[i2 * 3 + 2];
    // exact reference projection
    float ax = (FOCALF * x0) / z0, ay = (FOCALF * y0) / z0;
    float bx = (FOCALF * x1) / z1, by = (FOCALF * y1) / z1;
    float cx = (FOCALF * x2) / z2, cy = (FOCALF * y2) / z2;
    // edge vectors (identical rounding to reference's inline subtractions)
    float e0x = cx - bx, e0y = cy - by;   // edge for w0 (v1->v2), base b
    float e1x = ax - cx, e1y = ay - cy;   // edge for w1 (v2->v0), base c
    float e2x = bx - ax, e2y = by - ay;   // edge for w2 (v0->v1), base a
    float den = e2x * (cy - ay) - e2y * (cx - ax);   // == reference area tree
    if (!(fabsf(den) > EPSF)) den = 0.0f;
    float* o = fdata + ((size_t)t << 4);
    o[0]  = e0x; o[1]  = e0y; o[2]  = bx;  o[3]  = by;
    o[4]  = e1x; o[5]  = e1y; o[6]  = cx;  o[7]  = cy;
    o[8]  = e2x; o[9]  = e2y; o[10] = ax;  o[11] = ay;
    o[12] = den; o[13] = z0;  o[14] = z1;  o[15] = z2;
}

// one block = (image b, 16x16 pixel tile, chunk of 64 faces).
// Binning threads hold survivor data in registers and write it COMPACTED into
// LDS; the inner loop reads only LDS at wave-uniform addresses (broadcast).
__global__ __launch_bounds__(256) void pass1(const float* __restrict__ fdata,
                                             unsigned long long* __restrict__ zbest) {
#pragma clang fp contract(off)
    __shared__ float4 sface[CHUNK * 4];   // 4 KB compacted survivor data
    __shared__ int    sidx[CHUNK];
    __shared__ int    scnt;
    const int tid   = threadIdx.x;
    const int b     = blockIdx.x >> 6;
    const int tile  = blockIdx.x & 63;
    const int fbase = blockIdx.y * CHUNK;
    if (tid == 0) scnt = 0;
    __syncthreads();

    const int ix0 = (tile & 7) * 16, iy0 = (tile >> 3) * 16;
    const float pxmax = 1.0f - (2.0f * (float)ix0 + 1.0f) / (float)IMG;
    const float pxmin = 1.0f - (2.0f * (float)(ix0 + 15) + 1.0f) / (float)IMG;
    const float pymax = 1.0f - (2.0f * (float)iy0 + 1.0f) / (float)IMG;
    const float pymin = 1.0f - (2.0f * (float)(iy0 + 15) + 1.0f) / (float)IMG;

    // conservative half-plane binning: survive iff for all 3 edges,
    // max over tile rect of sign(den)*w_exact >= -SLACK
    if (tid < CHUNK && fbase + tid < F) {
        const int f = fbase + tid;
        const float4* fd4 = (const float4*)(fdata + (((size_t)b * F + f) << 4));
        float4 q0 = fd4[0], q1 = fd4[1], q2 = fd4[2], q3 = fd4[3];
        float den = q3.x;
        if (den != 0.0f) {
            float s = den > 0.0f ? 1.0f : -1.0f;
            bool pass = true;
            {
                float gx = s * q0.x, gy = s * q0.y;
                float pyc = gx >= 0.0f ? pymax : pymin;
                float pxc = gy >= 0.0f ? pxmin : pxmax;
                pass &= (gx * (pyc - q0.w) - gy * (pxc - q0.z)) >= -SLACK;
            }
            {
                float gx = s * q1.x, gy = s * q1.y;
                float pyc = gx >= 0.0f ? pymax : pymin;
                float pxc = gy >= 0.0f ? pxmin : pxmax;
                pass &= (gx * (pyc - q1.w) - gy * (pxc - q1.z)) >= -SLACK;
            }
            {
                float gx = s * q2.x, gy = s * q2.y;
                float pyc = gx >= 0.0f ? pymax : pymin;
                float pxc = gy >= 0.0f ? pxmin : pxmax;
                pass &= (gx * (pyc - q2.w) - gy * (pxc - q2.z)) >= -SLACK;
            }
            if (pass) {
                int slot = atomicAdd(&scnt, 1);
                sface[slot * 4 + 0] = q0;
                sface[slot * 4 + 1] = q1;
                sface[slot * 4 + 2] = q2;
                sface[slot * 4 + 3] = q3;
                sidx[slot] = f;
            }
        }
    }
    __syncthreads();
    const int cnt = scnt;

    const int dx = tid & 15, dy = tid >> 4;
    const int ix = ix0 + dx, iy = iy0 + dy;
    const float px = 1.0f - (2.0f * (float)ix + 1.0f) / (float)IMG;
    const float py = 1.0f - (2.0f * (float)iy + 1.0f) / (float)IMG;

    unsigned long long pmin = ~0ULL;
    #pragma unroll 4
    for (int i = 0; i < cnt; ++i) {
        float4 q0 = sface[i * 4 + 0];
        float4 q1 = sface[i * 4 + 1];
        float4 q2 = sface[i * 4 + 2];
        float4 q3 = sface[i * 4 + 3];
        const int fj = sidx[i];
        const float den = q3.x;
        // exact reference edge functions
        float w0 = q0.x * (py - q0.w) - q0.y * (px - q0.z);
        float w1 = q1.x * (py - q1.w) - q1.y * (px - q1.z);
        float w2 = q2.x * (py - q2.w) - q2.y * (px - q2.z);
        // s_i >= 0  <=>  w_i==0 || sign(w_i)==sign(den)   (den != 0 staged)
        unsigned ds = __float_as_uint(den) >> 31;
        bool in0 = (w0 == 0.0f) || ((__float_as_uint(w0) >> 31) == ds);
        bool in1 = (w1 == 0.0f) || ((__float_as_uint(w1) >> 31) == ds);
        bool in2 = (w2 == 0.0f) || ((__float_as_uint(w2) >> 31) == ds);
        if (in0 & in1 & in2) {
            // exact reference rounding for z (3 IEEE divides)
            float s0 = w0 / den, s1 = w1 / den, s2 = w2 / den;
            float z  = s0 * q3.y + s1 * q3.z + s2 * q3.w;
            if (z > 0.0f) {
                unsigned long long pk =
                    ((unsigned long long)__float_as_uint(z) << 32) | (unsigned)fj;
                pmin = pmin < pk ? pmin : pk;
            }
        }
    }
    if (pmin != ~0ULL) atomicMin(&zbest[b * NPIX + iy * IMG + ix], pmin);
}

// Unpack winner; recompute bary + dists from fdata (reference-rounded values).
__global__ __launch_bounds__(256) void pass2(const float* __restrict__ fdata,
                                             const unsigned long long* __restrict__ zbest,
                                             float* __restrict__ out) {
#pragma clang fp contract(off)
    const int gp = blockIdx.x * 256 + threadIdx.x;
    const int b  = gp >> 14;
    const int p  = gp & (NPIX - 1);
    const int ix = p & (IMG - 1), iy = p >> 7;

    unsigned long long packed = zbest[gp];
    float o_face = -1.0f, o_z = -1.0f, o_b0 = -1.0f, o_b1 = -1.0f,
          o_b2 = -1.0f, o_d = -1.0f;

    if (packed != ~0ULL) {
        const int   idx = (int)(unsigned)(packed & 0xffffffffu);
        const float z   = __uint_as_float((unsigned)(packed >> 32));
        const float px  = 1.0f - (2.0f * (float)ix + 1.0f) / (float)IMG;
        const float py  = 1.0f - (2.0f * (float)iy + 1.0f) / (float)IMG;

        const float4* fd4 = (const float4*)(fdata + (((size_t)b * F + idx) << 4));
        float4 q0 = fd4[0], q1 = fd4[1], q2 = fd4[2], q3 = fd4[3];
        float den = q3.x;
        float w0 = q0.x * (py - q0.w) - q0.y * (px - q0.z);
        float w1 = q1.x * (py - q1.w) - q1.y * (px - q1.z);
        float w2 = q2.x * (py - q2.w) - q2.y * (px - q2.z);
        float s0 = w0 / den, s1 = w1 / den, s2 = w2 / den;

        // a=(q2.z,q2.w)  b=(q0.z,q0.w)  c=(q1.z,q1.w): reference-rounded coords
        float d2 = fminf(fminf(seg_dist2(px, py, q2.z, q2.w, q0.z, q0.w),
                               seg_dist2(px, py, q0.z, q0.w, q1.z, q1.w)),
                         seg_dist2(px, py, q1.z, q1.w, q2.z, q2.w));
        o_face = (float)idx; o_z = z;
        o_b0 = s0; o_b1 = s1; o_b2 = s2;
        o_d = -d2;
    }

    out[gp]            = o_face;
    out[B * NPIX + gp] = o_z;
    const int bary_base = 2 * B * NPIX;
    out[bary_base + gp * 3 + 0] = o_b0;
    out[bary_base + gp * 3 + 1] = o_b1;
    out[bary_base + gp * 3 + 2] = o_b2;
    out[5 * B * NPIX + gp] = o_d;
}

} // namespace

extern "C" void kernel_launch(void* const* d_in, const int* in_sizes, int n_in,
                              void* d_out, int out_size, void* d_ws, size_t ws_size,
                              hipStream_t stream) {
    const float* verts = (const float*)d_in[0];  // (B,V,3) f32
    const int*   faces = (const int*)d_in[1];    // (F,3) i32
    float* out = (float*)d_out;

    unsigned long long* zbest = (unsigned long long*)d_ws;          // 512 KB
    float* fdata = (float*)((char*)d_ws + (size_t)B * NPIX * 8);    // 256 KB

    setup_clear<<<B * NPIX / 256, 256, 0, stream>>>(verts, faces, fdata, zbest);
    pass1<<<dim3(B * 64, NCHUNK), dim3(256), 0, stream>>>(fdata, zbest);
    pass2<<<dim3(B * NPIX / 256), dim3(256), 0, stream>>>(fdata, zbest, out);
}